// Round 6
// baseline (737.311 us; speedup 1.0000x reference)
//
#include <hip/hip_runtime.h>
#include <hip/hip_bf16.h>

typedef __attribute__((ext_vector_type(8))) short short8;
typedef __attribute__((ext_vector_type(4))) float floatx4;

#define S_LEN  50
#define BATCH  128
#define DIM    512
#define HID    512
#define G3     1536
#define VOCAB  30000
#define TOKENS 6400
#define NVB    235      // 128-wide v-chunks (ceil(30000/128))
#define NVC    470      // partial columns = NVB * 2 (two waves per v-chunk)

__device__ __forceinline__ float bf2f(short u) {
    union { unsigned int i; float f; } c;
    c.i = ((unsigned int)(unsigned short)u) << 16;
    return c.f;
}
__device__ __forceinline__ unsigned short f2bf(float x) {
    __hip_bfloat16 h = __float2bfloat16(x);
    unsigned short u;
    __builtin_memcpy(&u, &h, 2);
    return u;
}
__device__ __forceinline__ void gl_lds16(const void* g, void* l) {
    __builtin_amdgcn_global_load_lds(
        (const __attribute__((address_space(1))) void*)g,
        (__attribute__((address_space(3))) void*)l, 16, 0, 0);
}

// ---------------- f32 -> bf16 bulk convert (8 elems/thread) ----------------
__global__ void k_cvt_bf16(const float* __restrict__ src,
                           unsigned short* __restrict__ dst, int n8) {
    int g = blockIdx.x * 256 + threadIdx.x;
    if (g >= n8) return;
    const float* s = src + (size_t)g * 8;
    union { short8 v; unsigned short u[8]; } o;
#pragma unroll
    for (int i = 0; i < 8; ++i) o.u[i] = f2bf(s[i]);
    *(short8*)(dst + (size_t)g * 8) = o.v;
}

// ---------------- embedding gather + convert: X[token][512] bf16 ----------------
__global__ void k_gather_x(const float* __restrict__ emb, const int* __restrict__ idx,
                           unsigned short* __restrict__ X) {
    int g = blockIdx.x * 256 + threadIdx.x;   // 8-elem group; total TOKENS*DIM/8
    int token = g >> 6;                       // 64 groups per token
    int chunk = (g & 63) << 3;
    const float* src = emb + (size_t)idx[token] * DIM + chunk;
    union { short8 v; unsigned short u[8]; } o;
#pragma unroll
    for (int i = 0; i < 8; ++i) o.u[i] = f2bf(src[i]);
    *(short8*)(X + (size_t)token * DIM + chunk) = o.v;
}

// ---------------- GI = X @ W_ih^T + b_ih   [6400 x 1536] fp32 ----------------
// NT GEMM, bf16 MFMA 16x16x32. Block: 256 thr (4 waves), tile 64x64, BK=64.
__launch_bounds__(256)
__global__ void k_gemm_gi(const unsigned short* __restrict__ X,
                          const unsigned short* __restrict__ Wih,
                          const float* __restrict__ b_ih,
                          float* __restrict__ GI) {
    __shared__ unsigned short As[64][72];
    __shared__ unsigned short Bs[64][72];
    int m0 = blockIdx.x * 64;
    int n0 = blockIdx.y * 64;
    int t = threadIdx.x;
    int w = t >> 6, lane = t & 63;
    floatx4 zero = {0.f, 0.f, 0.f, 0.f};
    floatx4 acc[4];
#pragma unroll
    for (int i = 0; i < 4; ++i) acc[i] = zero;
    int srow = t >> 2, scol = (t & 3) * 16;
    for (int k0 = 0; k0 < DIM; k0 += 64) {
        *(short8*)&As[srow][scol]     = *(const short8*)(X   + (size_t)(m0 + srow) * DIM + k0 + scol);
        *(short8*)&As[srow][scol + 8] = *(const short8*)(X   + (size_t)(m0 + srow) * DIM + k0 + scol + 8);
        *(short8*)&Bs[srow][scol]     = *(const short8*)(Wih + (size_t)(n0 + srow) * DIM + k0 + scol);
        *(short8*)&Bs[srow][scol + 8] = *(const short8*)(Wih + (size_t)(n0 + srow) * DIM + k0 + scol + 8);
        __syncthreads();
#pragma unroll
        for (int kt = 0; kt < 2; ++kt) {
            short8 a = *(const short8*)&As[w * 16 + (lane & 15)][kt * 32 + (lane >> 4) * 8];
#pragma unroll
            for (int nt = 0; nt < 4; ++nt) {
                short8 b = *(const short8*)&Bs[nt * 16 + (lane & 15)][kt * 32 + (lane >> 4) * 8];
                acc[nt] = __builtin_amdgcn_mfma_f32_16x16x32_bf16(a, b, acc[nt], 0, 0, 0);
            }
        }
        __syncthreads();
    }
#pragma unroll
    for (int nt = 0; nt < 4; ++nt)
#pragma unroll
        for (int r = 0; r < 4; ++r) {
            int row = m0 + w * 16 + (lane >> 4) * 4 + r;
            int col = n0 + nt * 16 + (lane & 15);
            GI[(size_t)row * G3 + col] = acc[nt][r] + b_ih[col];
        }
}

// ---------------- GRU single step: h_t = GRUCell(h_{t-1}, GI_t) ----------------
__launch_bounds__(128)
__global__ void k_gru_step(const float* __restrict__ GI,
                           const unsigned short* __restrict__ Whh,
                           const float* __restrict__ b_hh,
                           float* __restrict__ hf,
                           const unsigned short* __restrict__ hin,
                           unsigned short* __restrict__ hout,
                           int s) {
    int t = threadIdx.x;
    int w = t >> 6, lane = t & 63;
    int bg = blockIdx.x & 7;      // batch group
    int hs = blockIdx.x >> 3;     // hidden slice (16 slices of 32)
    int jc = hs * 32 + w * 16 + (lane & 15);   // hidden unit this lane covers (N index)

    const unsigned short* pa  = hin + (size_t)(bg * 16 + (lane & 15)) * HID + (lane >> 4) * 8;
    const unsigned short* pb0 = Whh + (size_t)(0 * HID + jc) * DIM + (lane >> 4) * 8;
    const unsigned short* pb1 = Whh + (size_t)(1 * HID + jc) * DIM + (lane >> 4) * 8;
    const unsigned short* pb2 = Whh + (size_t)(2 * HID + jc) * DIM + (lane >> 4) * 8;

    floatx4 acc0 = {0.f, 0.f, 0.f, 0.f};
    floatx4 acc1 = {0.f, 0.f, 0.f, 0.f};
    floatx4 acc2 = {0.f, 0.f, 0.f, 0.f};
#pragma unroll
    for (int kt = 0; kt < 16; ++kt) {
        short8 a = *(const short8*)(pa + kt * 32);
        acc0 = __builtin_amdgcn_mfma_f32_16x16x32_bf16(a, *(const short8*)(pb0 + kt * 32), acc0, 0, 0, 0);
        acc1 = __builtin_amdgcn_mfma_f32_16x16x32_bf16(a, *(const short8*)(pb1 + kt * 32), acc1, 0, 0, 0);
        acc2 = __builtin_amdgcn_mfma_f32_16x16x32_bf16(a, *(const short8*)(pb2 + kt * 32), acc2, 0, 0, 0);
    }
    float bhr = b_hh[jc], bhz = b_hh[jc + 512], bhn = b_hh[jc + 1024];
#pragma unroll
    for (int r = 0; r < 4; ++r) {
        int brow = bg * 16 + (lane >> 4) * 4 + r;   // batch row (M index)
        int tok = s * BATCH + brow;
        const float* gi = GI + (size_t)tok * G3;
        float rg = 1.f / (1.f + __expf(-(gi[jc] + acc0[r] + bhr)));
        float zg = 1.f / (1.f + __expf(-(gi[jc + 512] + acc1[r] + bhz)));
        float ng = tanhf(gi[jc + 1024] + rg * (acc2[r] + bhn));
        size_t hidx = (size_t)brow * HID + jc;
        float hn = (1.f - zg) * ng + zg * hf[hidx];
        hf[hidx] = hn;
        hout[hidx] = f2bf(hn);
    }
}

// ---------------- decode: m97-structure 128x128 tile, global_load_lds(16) ----------------
// 256 thr = 4 waves in 2x2; wave owns 64x64 quadrant (4x4 MFMA frags).
// partial[tok][NVC]: column = nb*2 + wc.
__launch_bounds__(256)
__global__ void k_decode(const unsigned short* __restrict__ HS,
                         const unsigned short* __restrict__ Wout,
                         const float* __restrict__ b_out,
                         float* __restrict__ partial) {
    __shared__ unsigned short As[128 * 64];
    __shared__ unsigned short Bs[128 * 64];
    int m0 = blockIdx.x * 128;
    int nb = blockIdx.y;
    int n0 = nb * 128;
    int t = threadIdx.x, w = t >> 6, lane = t & 63;
    int wr = w >> 1, wc = w & 1;

    floatx4 zero = {0.f, 0.f, 0.f, 0.f};
    floatx4 acc[4][4];
#pragma unroll
    for (int mi = 0; mi < 4; ++mi)
#pragma unroll
        for (int ni = 0; ni < 4; ++ni) acc[mi][ni] = zero;

    int srow = lane >> 3;           // 0..7 within each 8-row staging group
    int scol = (lane & 7) * 8;      // shorts
    for (int k0 = 0; k0 < DIM; k0 += 64) {
        // stage A (128x64) and B (128x64), wave w covers rows [w*32, w*32+32)
#pragma unroll
        for (int i = 0; i < 4; ++i) {
            int rbase = w * 32 + i * 8;
            int ra = m0 + rbase + srow;
            gl_lds16(HS + (size_t)ra * DIM + k0 + scol, &As[rbase * 64]);
            int v = n0 + rbase + srow;
            if (v > VOCAB - 1) v = VOCAB - 1;   // clamp; masked in epilogue
            gl_lds16(Wout + (size_t)v * DIM + k0 + scol, &Bs[rbase * 64]);
        }
        __syncthreads();
#pragma unroll
        for (int kt = 0; kt < 2; ++kt) {
            short8 a[4], b[4];
#pragma unroll
            for (int mi = 0; mi < 4; ++mi)
                a[mi] = *(const short8*)&As[(wr * 64 + mi * 16 + (lane & 15)) * 64 + kt * 32 + (lane >> 4) * 8];
#pragma unroll
            for (int ni = 0; ni < 4; ++ni)
                b[ni] = *(const short8*)&Bs[(wc * 64 + ni * 16 + (lane & 15)) * 64 + kt * 32 + (lane >> 4) * 8];
#pragma unroll
            for (int mi = 0; mi < 4; ++mi)
#pragma unroll
                for (int ni = 0; ni < 4; ++ni)
                    acc[mi][ni] = __builtin_amdgcn_mfma_f32_16x16x32_bf16(a[mi], b[ni], acc[mi][ni], 0, 0, 0);
        }
        __syncthreads();
    }

    // epilogue: exp + per-token partial sums over this wave's 64 vocab cols
    float esum[4][4];   // [mi][r]
#pragma unroll
    for (int mi = 0; mi < 4; ++mi)
#pragma unroll
        for (int r = 0; r < 4; ++r) esum[mi][r] = 0.f;
#pragma unroll
    for (int ni = 0; ni < 4; ++ni) {
        int v = n0 + wc * 64 + ni * 16 + (lane & 15);
        bool ok = v < VOCAB;
        float bo = ok ? b_out[v] : 0.f;
#pragma unroll
        for (int mi = 0; mi < 4; ++mi)
#pragma unroll
            for (int r = 0; r < 4; ++r) {
                float logit = acc[mi][ni][r] + bo;
                esum[mi][r] += ok ? __expf(logit) : 0.f;
            }
    }
#pragma unroll
    for (int d = 1; d < 16; d <<= 1)
#pragma unroll
        for (int mi = 0; mi < 4; ++mi)
#pragma unroll
            for (int r = 0; r < 4; ++r) esum[mi][r] += __shfl_xor(esum[mi][r], d, 64);
    if ((lane & 15) == 0) {
#pragma unroll
        for (int mi = 0; mi < 4; ++mi)
#pragma unroll
            for (int r = 0; r < 4; ++r) {
                int tok = m0 + wr * 64 + mi * 16 + (lane >> 4) * 4 + r;
                partial[(size_t)tok * 512 + nb * 2 + wc] = esum[mi][r];
            }
    }
}

// ---------------- fixed-order reduce of partials -> lse ----------------
__global__ void k_reduce_lse(const float* __restrict__ partial, float* __restrict__ lse) {
    int tok = blockIdx.x * 4 + (threadIdx.x >> 6);
    int lane = threadIdx.x & 63;
    float s = 0.f;
    for (int j = lane; j < NVC; j += 64) s += partial[(size_t)tok * 512 + j];
#pragma unroll
    for (int d = 1; d < 64; d <<= 1) s += __shfl_xor(s, d, 64);
    if (lane == 0) lse[tok] = logf(s);
}

// ---------------- target logit: one wave per token ----------------
__global__ void k_tlogit(const unsigned short* __restrict__ HS,
                         const unsigned short* __restrict__ Wout,
                         const float* __restrict__ b_out,
                         const int* __restrict__ target,
                         float* __restrict__ tlg) {
    int tok = blockIdx.x * 4 + (threadIdx.x >> 6);
    int lane = threadIdx.x & 63;
    int tg = target[tok];
    short8 a = *(const short8*)(HS + (size_t)tok * DIM + lane * 8);
    short8 b = *(const short8*)(Wout + (size_t)tg * DIM + lane * 8);
    float s = 0.f;
#pragma unroll
    for (int i = 0; i < 8; ++i) s += bf2f(a[i]) * bf2f(b[i]);
#pragma unroll
    for (int d = 1; d < 64; d <<= 1) s += __shfl_xor(s, d, 64);
    if (lane == 0) tlg[tok] = s + b_out[tg];
}

// ---------------- loss + masked mean ----------------
__global__ void k_finalize(const float* __restrict__ lse, const float* __restrict__ tlg,
                           const int* __restrict__ target, float* __restrict__ out) {
    __shared__ float ssum[256];
    __shared__ float scnt[256];
    int t = threadIdx.x;
    float ls = 0.f, lc = 0.f;
    for (int i = t; i < TOKENS; i += 256) {
        int tg = target[i];
        float loss = (tg != 0) ? (lse[i] - tlg[i]) : 0.f;
        out[i] = loss;
        ls += loss;
        lc += (tg != 0) ? 1.f : 0.f;
    }
    ssum[t] = ls; scnt[t] = lc;
    __syncthreads();
    for (int d = 128; d > 0; d >>= 1) {
        if (t < d) { ssum[t] += ssum[t + d]; scnt[t] += scnt[t + d]; }
        __syncthreads();
    }
    if (t == 0) out[TOKENS] = ssum[0] / fmaxf(scnt[0], 1.f);
}

extern "C" void kernel_launch(void* const* d_in, const int* in_sizes, int n_in,
                              void* d_out, int out_size, void* d_ws, size_t ws_size,
                              hipStream_t stream) {
    const int*   review_input  = (const int*)d_in[2];
    const int*   review_target = (const int*)d_in[3];
    const float* word_emb      = (const float*)d_in[4];
    const float* W_ih          = (const float*)d_in[5];
    const float* W_hh          = (const float*)d_in[6];
    const float* b_ih          = (const float*)d_in[7];
    const float* b_hh          = (const float*)d_in[8];
    const float* W_out         = (const float*)d_in[9];
    const float* b_out         = (const float*)d_in[10];
    float* out = (float*)d_out;

    char* ws = (char*)d_ws;
    size_t off = 0;
    auto alloc = [&](size_t n) { char* p = ws + off; off += (n + 255) & ~(size_t)255; return p; };
    unsigned short* Xb    = (unsigned short*)alloc((size_t)TOKENS * DIM * 2);
    unsigned short* Wihb  = (unsigned short*)alloc((size_t)G3 * DIM * 2);
    unsigned short* Whhb  = (unsigned short*)alloc((size_t)G3 * HID * 2);
    unsigned short* Woutb = (unsigned short*)alloc((size_t)VOCAB * DIM * 2);
    unsigned short* HS    = (unsigned short*)alloc((size_t)TOKENS * HID * 2);
    unsigned short* hzero = (unsigned short*)alloc((size_t)BATCH * HID * 2);
    float* hf      = (float*)alloc((size_t)BATCH * HID * 4);
    float* GI      = (float*)alloc((size_t)TOKENS * G3 * 4);
    float* partial = (float*)alloc((size_t)TOKENS * 512 * 4);
    float* lse     = (float*)alloc((size_t)TOKENS * 4);
    float* tlg     = (float*)alloc((size_t)TOKENS * 4);
    (void)ws_size; (void)in_sizes; (void)n_in; (void)out_size;

    // weight conversions + embedding gather
    k_cvt_bf16<<<dim3((G3 * DIM / 8 + 255) / 256), dim3(256), 0, stream>>>(W_ih, Wihb, G3 * DIM / 8);
    k_cvt_bf16<<<dim3((G3 * HID / 8 + 255) / 256), dim3(256), 0, stream>>>(W_hh, Whhb, G3 * HID / 8);
    k_cvt_bf16<<<dim3((VOCAB * DIM / 8 + 255) / 256), dim3(256), 0, stream>>>(W_out, Woutb, VOCAB * DIM / 8);
    k_gather_x<<<dim3(TOKENS * DIM / 8 / 256), dim3(256), 0, stream>>>(word_emb, review_input, Xb);

    // GI = X @ W_ih^T + b_ih
    k_gemm_gi<<<dim3(TOKENS / 64, G3 / 64), dim3(256), 0, stream>>>(Xb, Wihb, b_ih, GI);

    // GRU recurrence: 50 per-step kernels; h carried in hf (fp32) and HS rows (bf16)
    hipMemsetAsync(hf, 0, (size_t)BATCH * HID * 4, stream);
    hipMemsetAsync(hzero, 0, (size_t)BATCH * HID * 2, stream);
    for (int s = 0; s < S_LEN; ++s) {
        const unsigned short* hin = s ? (HS + (size_t)(s - 1) * BATCH * HID) : hzero;
        unsigned short* hout = HS + (size_t)s * BATCH * HID;
        k_gru_step<<<dim3(128), dim3(128), 0, stream>>>(GI, Whhb, b_hh, hf, hin, hout, s);
    }

    // decode: partial exp-sums, reduce to lse, target logits, final loss
    k_decode<<<dim3(TOKENS / 128, NVB), dim3(256), 0, stream>>>(HS, Woutb, b_out, partial);
    k_reduce_lse<<<dim3(TOKENS / 4), dim3(256), 0, stream>>>(partial, lse);
    k_tlogit<<<dim3(TOKENS / 4), dim3(256), 0, stream>>>(HS, Woutb, b_out, review_target, tlg);
    k_finalize<<<dim3(1), dim3(256), 0, stream>>>(lse, tlg, review_target, out);
}